// Round 5
// baseline (702.142 us; speedup 1.0000x reference)
//
#include <hip/hip_runtime.h>
#include <cstddef>
#include <cstdint>

typedef unsigned short ushort_t;
typedef __attribute__((ext_vector_type(4))) float f32x4;
typedef __attribute__((ext_vector_type(8))) short bf16x8;

#define BB   8192
#define AA   16
#define BA   131072

// ---------------------------------------------------------------------------
// bf16 helpers
// ---------------------------------------------------------------------------
__device__ __forceinline__ float bf2f(ushort_t u) {
    union { float f; uint32_t i; } v; v.i = ((uint32_t)u) << 16; return v.f;
}
__device__ __forceinline__ ushort_t f2bf(float f) {
    union { float f; uint32_t i; } v; v.f = f;
    uint32_t r = v.i + 0x7fffu + ((v.i >> 16) & 1u);
    return (ushort_t)(r >> 16);
}
__device__ __forceinline__ void gload_lds16(const void* g, void* l) {
    __builtin_amdgcn_global_load_lds(
        (const __attribute__((address_space(1))) uint32_t*)g,
        (__attribute__((address_space(3))) uint32_t*)l, 16, 0, 0);
}

// ---------------------------------------------------------------------------
// 256x256 MFMA GEMM, BK=32, 8 waves (2Mx4N), 2-deep LDS ring (64 KB).
// Pattern per K-tile t: issue tile-(t+1) global loads EARLY, ds_read + MFMA
// tile t, (AF32: cvt+ds_write A(t+1)), one __syncthreads (its vmcnt(0) drain
// is cheap: loads had a whole compute phase to land). Compiler handles all
// fine-grained lgkmcnt interleave (m97-verified behavior).
// T2 XOR swizzle: logical 8-col granule gl of row stored at phys gl^s(row),
// s(row)=(row^(row>>2))&3 -> ds_read 2-way conflicts (free).
//   AF32: A is f32 (lda f32 elems), converted in-flight. Else A bf16 with
//   split: k<ksplit from Ax(lda), k>=ksplit from A2(lda2); ksplit%32==0.
//   Bt [>=bcol+256][K] bf16. C bf16, row stride ldc, N multiple of 256.
// Grid: 8*rpx*(1<<lgx) blocks, XCD-panel swizzle (bijective).
// ---------------------------------------------------------------------------
template<bool AF32, bool RELU>
__global__ __launch_bounds__(512)
void gemm256(const void* __restrict__ Ax, int lda,
             const ushort_t* __restrict__ A2, int lda2, int ksplit,
             const ushort_t* __restrict__ Bt,
             const float* __restrict__ bias,
             ushort_t* __restrict__ C, int ldc, int K, int lgx, int rpx)
{
    __shared__ ushort_t lds[32768];      // 2 bufs x (A 8192 + B 8192)

    const int tid  = threadIdx.x;
    const int w    = tid >> 6;
    const int lane = tid & 63;
    const int wm   = w >> 2;             // 0..1
    const int wn   = w & 3;              // 0..3
    const int fr   = lane & 15;
    const int fq   = lane >> 4;

    const int bid  = blockIdx.x;
    const int xcd  = bid & 7;
    const int slot = bid >> 3;
    const int x    = slot & ((1 << lgx) - 1);
    const int y    = xcd * rpx + (slot >> lgx);
    const size_t brow = (size_t)y * 256;
    const int    bcol = x * 256;

    const int NT = K >> 5;

    f32x4 acc[8][4];
#pragma unroll
    for (int m = 0; m < 8; ++m)
#pragma unroll
        for (int n = 0; n < 4; ++n) acc[m][n] = (f32x4){0.f, 0.f, 0.f, 0.f};

    // A-f32 staging geometry: 2 threads/row, 16 f32 each
    const int arow  = tid >> 1;          // 0..255
    const int ahalf = tid & 1;
    const int as    = (arow ^ (arow >> 2)) & 3;
    float4 areg[4];

    auto stage_load = [&](int k0) {
        const int base = ((k0 >> 5) & 1) << 14;
        // B: 2 gload_lds, inverse-swizzled source
#pragma unroll
        for (int r = 0; r < 2; ++r) {
            const int gi  = r * 512 + tid;       // 0..1023
            const int row = gi >> 2;
            const int g   = gi & 3;
            const int s   = (row ^ (row >> 2)) & 3;
            const int col = ((g ^ s) << 3);
            gload_lds16(Bt + (size_t)(bcol + row) * K + k0 + col,
                        &lds[base + 8192 + gi * 8]);
        }
        if (AF32) {
            const float* Af  = (const float*)Ax;
            const float* src = Af + (brow + arow) * (size_t)lda + k0 + ahalf * 16;
#pragma unroll
            for (int i = 0; i < 4; ++i)
                areg[i] = *(const float4*)(src + i * 4);
        } else {
#pragma unroll
            for (int r = 0; r < 2; ++r) {
                const int gi  = r * 512 + tid;
                const int row = gi >> 2;
                const int g   = gi & 3;
                const int s   = (row ^ (row >> 2)) & 3;
                const int col = ((g ^ s) << 3);
                const ushort_t* src;
                if (k0 >= ksplit)
                    src = A2 + (brow + row) * (size_t)lda2 + (k0 - ksplit) + col;
                else
                    src = (const ushort_t*)Ax + (brow + row) * (size_t)lda + k0 + col;
                gload_lds16(src, &lds[base + gi * 8]);
            }
        }
    };

    auto stage_write = [&](int k0) {     // AF32 only: cvt + swizzled ds_write
        if (AF32) {
            const int base = ((k0 >> 5) & 1) << 14;
#pragma unroll
            for (int j = 0; j < 2; ++j) {
                ushort_t tmp[8];
                const float* f = (const float*)&areg[j * 2];
#pragma unroll
                for (int e = 0; e < 8; ++e) tmp[e] = f2bf(f[e]);
                const int gl = ahalf * 2 + j;
                const int p  = gl ^ as;
                *(bf16x8*)&lds[base + (arow * 4 + p) * 8] = *(const bf16x8*)tmp;
            }
        }
    };

    stage_load(0);
    stage_write(0);
    __syncthreads();                     // tile 0 resident

    const int sa = (fr ^ (fr >> 2)) & 3;
    const int pc = ((fq ^ sa) & 3) << 3;

    for (int t = 0; t < NT; ++t) {
        if (t + 1 < NT) stage_load((t + 1) << 5);   // issue early (T14)

        const int base = (t & 1) << 14;
        bf16x8 a[8], b[4];
#pragma unroll
        for (int m = 0; m < 8; ++m)
            a[m] = *(const bf16x8*)&lds[base + (wm * 128 + m * 16 + fr) * 32 + pc];
#pragma unroll
        for (int n = 0; n < 4; ++n)
            b[n] = *(const bf16x8*)&lds[base + 8192 + (wn * 64 + n * 16 + fr) * 32 + pc];

        __builtin_amdgcn_s_setprio(1);
#pragma unroll
        for (int m = 0; m < 8; ++m)
#pragma unroll
            for (int n = 0; n < 4; ++n)
                acc[m][n] = __builtin_amdgcn_mfma_f32_16x16x32_bf16(
                    a[m], b[n], acc[m][n], 0, 0, 0);
        __builtin_amdgcn_s_setprio(0);

        if (t + 1 < NT) stage_write((t + 1) << 5);  // write late; loads landed
        __syncthreads();                 // drains: next tile fully resident
    }

    // epilogue: C/D layout col=lane&15, row=(lane>>4)*4+r ; bias (+ReLU)
#pragma unroll
    for (int m = 0; m < 8; ++m) {
        const size_t rowb = brow + wm * 128 + m * 16 + fq * 4;
#pragma unroll
        for (int n = 0; n < 4; ++n) {
            const int col = bcol + wn * 64 + n * 16 + fr;
            const float bv = bias[col];
#pragma unroll
            for (int r = 0; r < 4; ++r) {
                float v = acc[m][n][r] + bv;
                if (RELU) v = fmaxf(v, 0.f);
                C[(rowb + r) * (size_t)ldc + col] = f2bf(v);
            }
        }
    }
}

// ---------------------------------------------------------------------------
// 128x128 MFMA GEMM (proven round-2/3/4 kernel) for small-N dispatches.
// ---------------------------------------------------------------------------
template<bool OBF16, bool RELU>
__global__ __launch_bounds__(256)
void gemm_mfma(const ushort_t* __restrict__ A, int lda,
               const ushort_t* __restrict__ A2, int lda2, int ksplit,
               const ushort_t* __restrict__ Bt,
               const float* __restrict__ bias,
               void* __restrict__ C, int ldc, int N, int K, int lgx)
{
    __shared__ ushort_t As[2][128 * 64];
    __shared__ ushort_t Bs[2][128 * 64];

    const int tid  = threadIdx.x;
    const int w    = tid >> 6;
    const int lane = tid & 63;
    const int wm   = w >> 1;
    const int wn   = w & 1;

    const int bid  = blockIdx.x;
    const int xcd  = bid & 7;
    const int slot = bid >> 3;
    const int x    = slot & ((1 << lgx) - 1);
    const int y    = xcd * 128 + (slot >> lgx);
    const size_t brow = (size_t)y * 128;
    const int    bcol = x * 128;

    const int fr   = lane & 15;
    const int fq   = lane >> 4;
    const int srow = lane >> 3;
    const int scol = (lane & 7) << 3;

    f32x4 acc[4][4];
#pragma unroll
    for (int i = 0; i < 4; ++i)
#pragma unroll
        for (int j = 0; j < 4; ++j) acc[i][j] = (f32x4){0.f, 0.f, 0.f, 0.f};

    const int NT = K >> 6;

    auto stage = [&](int buf, int k0) {
#pragma unroll
        for (int i = 0; i < 4; ++i) {
            const int c = (w << 2) + i;
            const int r = (c << 3) + srow;
            const ushort_t* asrc;
            if (k0 >= ksplit)
                asrc = A2 + (brow + r) * (size_t)lda2 + (k0 - ksplit) + scol;
            else
                asrc = A  + (brow + r) * (size_t)lda  + k0 + scol;
            gload_lds16(asrc, &As[buf][(c << 9) + lane * 8]);
            gload_lds16(Bt + (size_t)(bcol + r) * K + k0 + scol,
                        &Bs[buf][(c << 9) + lane * 8]);
        }
    };

    stage(0, 0);
    __syncthreads();

    for (int t = 0; t < NT; ++t) {
        const int cur = t & 1;
        if (t + 1 < NT) stage(cur ^ 1, (t + 1) << 6);
#pragma unroll
        for (int kk = 0; kk < 2; ++kk) {
            bf16x8 a[4], b[4];
#pragma unroll
            for (int f = 0; f < 4; ++f) {
                a[f] = *(const bf16x8*)&As[cur][(wm * 64 + f * 16 + fr) * 64 + kk * 32 + fq * 8];
                b[f] = *(const bf16x8*)&Bs[cur][(wn * 64 + f * 16 + fr) * 64 + kk * 32 + fq * 8];
            }
#pragma unroll
            for (int fm = 0; fm < 4; ++fm)
#pragma unroll
                for (int fn = 0; fn < 4; ++fn)
                    acc[fm][fn] = __builtin_amdgcn_mfma_f32_16x16x32_bf16(
                        a[fm], b[fn], acc[fm][fn], 0, 0, 0);
        }
        __syncthreads();
    }

#pragma unroll
    for (int fm = 0; fm < 4; ++fm) {
        const size_t rowb = brow + wm * 64 + fm * 16 + fq * 4;
#pragma unroll
        for (int fn = 0; fn < 4; ++fn) {
            const int col = bcol + wn * 64 + fn * 16 + fr;
            if (col < N) {
                const float bv = bias[col];
#pragma unroll
                for (int r = 0; r < 4; ++r) {
                    float v = acc[fm][fn][r] + bv;
                    if (RELU) v = fmaxf(v, 0.f);
                    const size_t idx = (rowb + r) * (size_t)ldc + col;
                    if (OBF16) ((ushort_t*)C)[idx] = f2bf(v);
                    else       ((float*)C)[idx]    = v;
                }
            }
        }
    }
}

// ---------------------------------------------------------------------------
// small prep kernels
// ---------------------------------------------------------------------------
__global__ __launch_bounds__(256)
void transpose_w(const float* __restrict__ W, ushort_t* __restrict__ Wt,
                 int K, int N, int Npad)
{
    int idx = blockIdx.x * 256 + threadIdx.x;
    if (idx >= Npad * K) return;
    int n = idx / K, k = idx - n * K;
    float v = (n < N) ? W[(size_t)k * N + n] : 0.f;
    Wt[idx] = f2bf(v);
}

__global__ __launch_bounds__(256)
void transpose_wk(const float* __restrict__ W, ushort_t* __restrict__ Wt,
                  int Ksrc, int N, int ldk, int kOff, float sign)
{
    int idx = blockIdx.x * 256 + threadIdx.x;
    if (idx >= N * Ksrc) return;
    int n = idx / Ksrc, k = idx - n * Ksrc;
    Wt[(size_t)n * ldk + kOff + k] = f2bf(sign * W[(size_t)k * N + n]);
}

__global__ __launch_bounds__(256)
void conv_f32_bf16(const float* __restrict__ src, ushort_t* __restrict__ dst)
{
    size_t q = (size_t)blockIdx.x * 256 + threadIdx.x;
    float4 v = ((const float4*)src)[q];
    ushort_t* d = dst + q * 4;
    d[0] = f2bf(v.x); d[1] = f2bf(v.y); d[2] = f2bf(v.z); d[3] = f2bf(v.w);
}

// g1bias = [bt1(512) | bp1(512)]
__global__ void pack_cat2(const float* __restrict__ a, const float* __restrict__ b,
                          float* __restrict__ o)
{
    int j = blockIdx.x * 256 + threadIdx.x;
    if (j < 512) o[j] = a[j];
    else if (j < 1024) o[j] = b[j - 512];
}

// pbias = [bk(32) | bq(32) | bv(128) | 0(64)]
__global__ void pack_bias(const float* __restrict__ bk, const float* __restrict__ bq,
                          const float* __restrict__ bv, float* __restrict__ pb)
{
    int j = threadIdx.x;
    float v = 0.f;
    if      (j < 32)  v = bk[j];
    else if (j < 64)  v = bq[j - 32];
    else if (j < 192) v = bv[j - 64];
    pb[j] = v;
}

__global__ void make_cbias(const float* __restrict__ bt2, const float* __restrict__ bp3,
                           float* __restrict__ cb)
{
    int j = threadIdx.x;
    cb[j] = bt2[j] - bp3[j];
}

// ---------------------------------------------------------------------------
// int_imp[b,a] = softmax_a( mean_c diff[b,a,c]^2 ), diff bf16 [BB,AA,128]
// ---------------------------------------------------------------------------
__global__ __launch_bounds__(64)
void mse_softmax(const ushort_t* __restrict__ diff, float* __restrict__ int_imp)
{
    const int b = blockIdx.x, lane = threadIdx.x;
    __shared__ float m[AA];
    for (int a = 0; a < AA; ++a) {
        const uint32_t u = *(const uint32_t*)(diff + ((size_t)b * AA + a) * 128 + lane * 2);
        float d0 = bf2f((ushort_t)(u & 0xffff));
        float d1 = bf2f((ushort_t)(u >> 16));
        float s = d0 * d0 + d1 * d1;
#pragma unroll
        for (int off = 32; off > 0; off >>= 1) s += __shfl_down(s, off);
        if (lane == 0) m[a] = s * (1.f / 128.f);
    }
    __syncthreads();
    if (lane == 0) {
        float mx = -1e30f;
#pragma unroll
        for (int a = 0; a < AA; ++a) mx = fmaxf(mx, m[a]);
        float e[AA], den = 0.f;
#pragma unroll
        for (int a = 0; a < AA; ++a) { e[a] = __expf(m[a] - mx); den += e[a]; }
        float inv = 1.f / den;
#pragma unroll
        for (int a = 0; a < AA; ++a) int_imp[(size_t)b * AA + a] = e[a] * inv;
    }
}

// ---------------------------------------------------------------------------
// attention: kvq packed [BA][192] = [key(32)|qry(32)|val(128)] per row.
// ---------------------------------------------------------------------------
__global__ __launch_bounds__(256)
void attn_apply(const ushort_t* __restrict__ kvq, const float* __restrict__ Wa,
                const float* __restrict__ ba, const float* __restrict__ iimp,
                ushort_t* __restrict__ applied)
{
    const int b = blockIdx.x, t = threadIdx.x;
    __shared__ float klds[512], qlds[512];
    __shared__ ushort_t vlds[2048];
    __shared__ float part[16][17];
    __shared__ float kp[16];
    __shared__ float attn[16][17];

    for (int i = t; i < 512; i += 256) {
        int a = i >> 5, c = i & 31;
        const size_t base = ((size_t)b * AA + a) * 192;
        klds[i] = bf2f(kvq[base + c]);
        qlds[i] = bf2f(kvq[base + 32 + c]);
    }
    for (int i = t; i < 2048; i += 256) {
        int j = i >> 7, v = i & 127;
        vlds[i] = kvq[((size_t)b * AA + j) * 192 + 64 + v];
    }
    __syncthreads();

    {
        int j = t & 15, seg = t >> 4;
        float s = 0.f;
        for (int c = seg * 32; c < seg * 32 + 32; ++c)
            s += klds[c] * Wa[(32 + c) * 16 + j];
        part[j][seg] = s;
    }
    __syncthreads();
    if (t < 16) {
        float s = 0.f;
#pragma unroll
        for (int seg = 0; seg < 16; ++seg) s += part[t][seg];
        kp[t] = s;
    }
    __syncthreads();

    {
        int i = t >> 4, j = t & 15;
        float s = 0.f;
#pragma unroll
        for (int q = 0; q < 32; ++q) s += qlds[i * 32 + q] * Wa[q * 16 + j];
        attn[i][j] = s + kp[j] + ba[j];
    }
    __syncthreads();
    if (t < 16) {
        float mx = -1e30f;
#pragma unroll
        for (int j = 0; j < 16; ++j) mx = fmaxf(mx, attn[t][j]);
        float e[16], den = 0.f;
#pragma unroll
        for (int j = 0; j < 16; ++j) { e[j] = __expf(attn[t][j] - mx); den += e[j]; }
        float inv = 1.f / den;
#pragma unroll
        for (int j = 0; j < 16; ++j)
            attn[t][j] = e[j] * inv + 0.5f * iimp[b * 16 + j];
    }
    __syncthreads();

    for (int o = t; o < 2048; o += 256) {
        int i = o >> 7, v = o & 127;
        float s = 0.f;
#pragma unroll
        for (int j = 0; j < 16; ++j) s += attn[i][j] * bf2f(vlds[j * 128 + v]);
        applied[((size_t)b * AA + i) * 128 + v] = f2bf(s);
    }
}

// ---------------------------------------------------------------------------
// launch
// ---------------------------------------------------------------------------
extern "C" void kernel_launch(void* const* d_in, const int* in_sizes, int n_in,
                              void* d_out, int out_size, void* d_ws, size_t ws_size,
                              hipStream_t stream)
{
    const float* x      = (const float*)d_in[0];
    const float* hidden = (const float*)d_in[1];
    const float* Wk  = (const float*)d_in[2];
    const float* bk  = (const float*)d_in[3];
    const float* Wv  = (const float*)d_in[4];
    const float* bv  = (const float*)d_in[5];
    const float* Wq  = (const float*)d_in[6];
    const float* bq  = (const float*)d_in[7];
    const float* Wa  = (const float*)d_in[8];
    const float* ba  = (const float*)d_in[9];
    const float* Wt1 = (const float*)d_in[10];
    const float* bt1 = (const float*)d_in[11];
    const float* Wt2 = (const float*)d_in[12];
    const float* bt2 = (const float*)d_in[13];
    const float* Wp1 = (const float*)d_in[14];
    const float* bp1 = (const float*)d_in[15];
    const float* Wp2 = (const float*)d_in[16];
    const float* bp2 = (const float*)d_in[17];
    const float* Wp3 = (const float*)d_in[18];
    const float* bp3 = (const float*)d_in[19];
    const float* Wc  = (const float*)d_in[20];
    const float* bc  = (const float*)d_in[21];
    const float* W2  = (const float*)d_in[22];
    const float* b2  = (const float*)d_in[23];

    float*    out = (float*)d_out;
    ushort_t* ws  = (ushort_t*)d_ws;

    // ---- workspace (ushort elements) ------------------------------------
    ushort_t* ht2  = ws;                        // [BA*1024] = [h_t | h_p1]
    ushort_t* hp2  = ht2 + (size_t)BA * 1024;   // [BA*512]
    ushort_t* diff = hp2 + (size_t)BA * 512;    // [BA*128]
    ushort_t* WT   = diff + (size_t)BA * 128;
    // phase-2 aliases inside ht2 (dead after diff GEMM) / hp2 (dead too)
    ushort_t* kvq     = ht2;                          // BA*192
    ushort_t* applied = ht2 + (size_t)BA * 192;       // BA*128
    ushort_t* comb    = ht2 + (size_t)BA * 320;       // BA*256
    ushort_t* hiddenb = hp2;                          // BA*256

    ushort_t* Bg1  = WT;                    // 1024*512  [Wt1^T ; Wp1^T]
    ushort_t* Wp2t = Bg1  + 1024 * 512;     // 512*512
    ushort_t* Dt   = Wp2t + 512 * 512;      // 128*1024  [Wt2^T | -Wp3^T]
    ushort_t* Wkvq = Dt   + 128 * 1024;     // 256*256
    ushort_t* Wct  = Wkvq + 256 * 256;      // 256*384
    ushort_t* W2t  = Wct  + 256 * 384;      // 128*256
    float* g1bias = (float*)(W2t + 128 * 256);
    float* pbias  = g1bias + 1024;
    float* cbias  = pbias + 256;
    float* iimp   = cbias + 128;            // BB*AA floats

    const dim3 blk(256);
    const int BIG = 1 << 30;

    // ---- weight prep -----------------------------------------------------
    transpose_w<<<1024, blk, 0, stream>>>(Wt1, Bg1,             512, 512, 512);
    transpose_w<<<1024, blk, 0, stream>>>(Wp1, Bg1 + 512 * 512, 512, 512, 512);
    transpose_w<<<1024, blk, 0, stream>>>(Wp2, Wp2t, 512, 512, 512);
    transpose_wk<<<256, blk, 0, stream>>>(Wt2, Dt, 512, 128, 1024, 0,    1.f);
    transpose_wk<<<256, blk, 0, stream>>>(Wp3, Dt, 512, 128, 1024, 512, -1.f);
    transpose_w<<<32,  blk, 0, stream>>>(Wk, Wkvq + 0 * 256,   256, 32, 32);
    transpose_w<<<32,  blk, 0, stream>>>(Wq, Wkvq + 32 * 256,  256, 32, 32);
    transpose_w<<<128, blk, 0, stream>>>(Wv, Wkvq + 64 * 256,  256, 128, 128);
    transpose_w<<<64,  blk, 0, stream>>>(Wk, Wkvq + 192 * 256, 256, 0, 64);   // zero pad
    transpose_w<<<384, blk, 0, stream>>>(Wc, Wct, 384, 256, 256);
    transpose_w<<<128, blk, 0, stream>>>(W2, W2t, 256, 64, 128);
    pack_cat2<<<4, 256, 0, stream>>>(bt1, bp1, g1bias);
    pack_bias<<<1, 256, 0, stream>>>(bk, bq, bv, pbias);
    make_cbias<<<1, 128, 0, stream>>>(bt2, bp3, cbias);

    // ---- phase 1: predictors ---------------------------------------------
    // [h_t | h_p1] = relu(x @ [Wt1|Wp1] + [bt1|bp1])   (f32 A, fused cvt)
    gemm256<true, true><<<2048, 512, 0, stream>>>(
        x, 512, nullptr, 0, BIG, Bg1, g1bias, ht2, 1024, 512, 2, 64);
    // h_p2 = relu(h_p1 @ Wp2 + bp2)
    gemm256<false, true><<<1024, 512, 0, stream>>>(
        ht2 + 512, 1024, nullptr, 0, BIG, Wp2t, bp2, hp2, 512, 512, 1, 64);
    // diff = [h_t | h_p2] @ [Wt2;-Wp3] + (bt2-bp3)
    gemm_mfma<true, false><<<1024, blk, 0, stream>>>(
        ht2, 1024, hp2, 512, 512, Dt, cbias, diff, 128, 128, 1024, 0);
    mse_softmax<<<BB, 64, 0, stream>>>(diff, iimp);

    // ---- phase 2: communicate --------------------------------------------
    conv_f32_bf16<<<32768, blk, 0, stream>>>(hidden, hiddenb);
    gemm_mfma<true, false><<<2048, blk, 0, stream>>>(
        hiddenb, 256, hiddenb, 256, BIG, Wkvq, pbias, kvq, 192, 192, 256, 1);
    attn_apply<<<BB, blk, 0, stream>>>(kvq, Wa, ba, iimp, applied);

    // ---- phase 3: combine + head -----------------------------------------
    // comb = relu([applied|hidden] @ Wc + bc)
    gemm256<false, true><<<512, 512, 0, stream>>>(
        applied, 128, hiddenb, 256, 128, Wct, bc, comb, 256, 384, 0, 64);
    // out = comb @ W2 + b2 (f32)
    gemm_mfma<false, false><<<1024, blk, 0, stream>>>(
        comb, 256, comb, 256, BIG, W2t, b2, out, 64, 64, 256, 0);
}

// Round 6
// 645.458 us; speedup vs baseline: 1.0878x; 1.0878x over previous
//
#include <hip/hip_runtime.h>
#include <cstddef>
#include <cstdint>

typedef unsigned short ushort_t;
typedef __attribute__((ext_vector_type(4))) float f32x4;
typedef __attribute__((ext_vector_type(8))) short bf16x8;

#define BB   8192
#define AA   16
#define BA   131072

// ---------------------------------------------------------------------------
// bf16 helpers
// ---------------------------------------------------------------------------
__device__ __forceinline__ float bf2f(ushort_t u) {
    union { float f; uint32_t i; } v; v.i = ((uint32_t)u) << 16; return v.f;
}
__device__ __forceinline__ ushort_t f2bf(float f) {
    union { float f; uint32_t i; } v; v.f = f;
    uint32_t r = v.i + 0x7fffu + ((v.i >> 16) & 1u);
    return (ushort_t)(r >> 16);
}
__device__ __forceinline__ void gload_lds16(const void* g, void* l) {
    __builtin_amdgcn_global_load_lds(
        (const __attribute__((address_space(1))) uint32_t*)g,
        (__attribute__((address_space(3))) uint32_t*)l, 16, 0, 0);
}

// ---------------------------------------------------------------------------
// 8-phase 256x256 MFMA GEMM (m201-style port), BK=64, 8 waves (2Mx4N),
// 2 K-tile LDS bufs (128 KB). Iter i computes tiles e=2i (buf0), o=2i+1
// (buf1) in 8 quadrant-phases. Phase body: {q0 only: vmcnt(6)+bar, read all
// 8 B-frags to regs} + 4 A-frag ds_reads + stage {1 A-strip + 1 B-chunk}
// into the region freed by the PREVIOUS phase's end barrier + bar +
// setprio(1) 16 MFMA setprio(0) + bar. vmcnt never drained mid-loop.
// Stage map (global phase g=h*4+q): g0:(o,s3,c3)  g1..g4:(e+2, s/c g-1)
// g5..g7:(o+2, s/c q-1). A-strip s = rows [s*32,s*32+32)+[128+s*32,..+32)
// (8KB, freed after quadrant s); B-chunk c = rows [c*64,c*64+64) (B freed
// entirely after q0's reg-read).
// LDS XOR swizzle: granule p at row holds logical granule p^(row&7);
// inverse-swizzled global source (round-5-refcheck-proven), swizzled reads.
//   A: k<ksplit from A(lda) else A2(lda2); ksplit%64==0. Bt [N][K] bf16.
//   M%256==0, N%256==0, K%128==0. C bf16 (+bias, opt ReLU), stride ldc.
// Grid: 8*rpx*(1<<lgx), XCD-panel swizzle.
// ---------------------------------------------------------------------------
template<bool RELU>
__global__ __launch_bounds__(512, 2)
void gemm8p(const ushort_t* __restrict__ A, int lda,
            const ushort_t* __restrict__ A2, int lda2, int ksplit,
            const ushort_t* __restrict__ Bt,
            const float* __restrict__ bias,
            ushort_t* __restrict__ C, int ldc, int K, int lgx, int rpx)
{
    __shared__ ushort_t lds[65536];   // 2 bufs x (A 16384 + B 16384) ushorts

    const int tid  = threadIdx.x;
    const int w    = tid >> 6;
    const int lane = tid & 63;
    const int wm   = w >> 2;          // 0..1
    const int wn   = w & 3;           // 0..3
    const int fr   = lane & 15;
    const int fq   = lane >> 4;

    const int bid  = blockIdx.x;
    const int xcd  = bid & 7;
    const int slot = bid >> 3;
    const int x    = slot & ((1 << lgx) - 1);
    const int y    = xcd * rpx + (slot >> lgx);
    const size_t brow = (size_t)y * 256;
    const int    bcol = x * 256;

    const int NT = K >> 6;            // K-tiles (even)
    const int NI = NT >> 1;

    // staging geometry (per thread): 8 granule-threads per 64-elem row
    const int srl = tid >> 3;         // 0..63 row-local
    const int spg = tid & 7;          // phys granule

    f32x4 acc[8][4];
#pragma unroll
    for (int m = 0; m < 8; ++m)
#pragma unroll
        for (int n = 0; n < 4; ++n) acc[m][n] = (f32x4){0.f, 0.f, 0.f, 0.f};

    // stage A-strip s of tile T into buf bi (1 gload_lds/thread = 8KB)
    auto stageA = [&](int T, int s, int bi) {
        const int k0  = T << 6;
        const int row = (srl < 32) ? s * 32 + srl : 128 + s * 32 + (srl - 32);
        const int col = ((spg ^ (row & 7)) << 3);
        const ushort_t* src;
        if (k0 >= ksplit) src = A2 + (brow + row) * (size_t)lda2 + (k0 - ksplit) + col;
        else              src = A  + (brow + row) * (size_t)lda  + k0 + col;
        gload_lds16(src, &lds[(bi << 15) + row * 64 + spg * 8]);
    };
    // stage B-chunk c of tile T (1 gload_lds/thread = 8KB)
    auto stageB = [&](int T, int c, int bi) {
        const int k0  = T << 6;
        const int row = c * 64 + srl;
        const int col = ((spg ^ (row & 7)) << 3);
        gload_lds16(Bt + (size_t)(bcol + row) * K + k0 + col,
                    &lds[(bi << 15) + 16384 + row * 64 + spg * 8]);
    };

    // ---- prologue: tile0 (8 units), tile1 first 6 units ------------------
    stageA(0, 0, 0); stageB(0, 0, 0);
    stageA(0, 1, 0); stageB(0, 1, 0);
    stageA(0, 2, 0); stageB(0, 2, 0);
    stageA(0, 3, 0); stageB(0, 3, 0);
    stageA(1, 0, 1); stageB(1, 0, 1);
    stageA(1, 1, 1); stageB(1, 1, 1);
    stageA(1, 2, 1); stageB(1, 2, 1);

    bf16x8 breg[4][2];

    for (int i = 0; i < NI; ++i) {
        const bool more = (i + 1 < NI);
#pragma unroll
        for (int h = 0; h < 2; ++h) {          // h=0: tile e (buf0); h=1: o (buf1)
            const int bufA = h << 15;
            const int bufB = (h << 15) + 16384;
#pragma unroll
            for (int q = 0; q < 4; ++q) {
                if (q == 0) {
                    // current tile fully resident after this wait+barrier
                    if (h == 0 || more) asm volatile("s_waitcnt vmcnt(6)" ::: "memory");
                    else                asm volatile("s_waitcnt vmcnt(0)" ::: "memory");
                    __builtin_amdgcn_sched_barrier(0);
                    __builtin_amdgcn_s_barrier();
                    // read ALL B-frags of this tile into registers
#pragma unroll
                    for (int n = 0; n < 4; ++n)
#pragma unroll
                        for (int kk = 0; kk < 2; ++kk) {
                            const int row = wn * 64 + n * 16 + fr;
                            const int gp  = ((kk * 4 + fq) ^ (row & 7)) << 3;
                            breg[n][kk] = *(const bf16x8*)&lds[bufB + row * 64 + gp];
                        }
                }
                // A-frags for this quadrant (m = 2q, 2q+1)
                bf16x8 areg[2][2];
#pragma unroll
                for (int j = 0; j < 2; ++j)
#pragma unroll
                    for (int kk = 0; kk < 2; ++kk) {
                        const int row = wm * 128 + (2 * q + j) * 16 + fr;
                        const int gp  = ((kk * 4 + fq) ^ (row & 7)) << 3;
                        areg[j][kk] = *(const bf16x8*)&lds[bufA + row * 64 + gp];
                    }
                // stage (into region freed by previous phase's end barrier)
                if (h == 0) {
                    if (q == 0)      { stageA(2*i+1, 3, 1); stageB(2*i+1, 3, 1); }
                    else if (more)   { stageA(2*i+2, q-1, 0); stageB(2*i+2, q-1, 0); }
                } else {
                    if (q == 0) { if (more) { stageA(2*i+2, 3, 0); stageB(2*i+2, 3, 0); } }
                    else        { if (more) { stageA(2*i+3, q-1, 1); stageB(2*i+3, q-1, 1); } }
                }
                __builtin_amdgcn_s_barrier();
                __builtin_amdgcn_s_setprio(1);
#pragma unroll
                for (int j = 0; j < 2; ++j)
#pragma unroll
                    for (int n = 0; n < 4; ++n)
#pragma unroll
                        for (int kk = 0; kk < 2; ++kk)
                            acc[2*q+j][n] = __builtin_amdgcn_mfma_f32_16x16x32_bf16(
                                areg[j][kk], breg[n][kk], acc[2*q+j][n], 0, 0, 0);
                __builtin_amdgcn_s_setprio(0);
                __builtin_amdgcn_s_barrier();
            }
        }
    }

    // epilogue: C/D layout col=lane&15, row=(lane>>4)*4+r
#pragma unroll
    for (int m = 0; m < 8; ++m) {
        const size_t rowb = brow + wm * 128 + m * 16 + fq * 4;
#pragma unroll
        for (int n = 0; n < 4; ++n) {
            const int col = bcol + wn * 64 + n * 16 + fr;
            const float bv = bias[col];
#pragma unroll
            for (int r = 0; r < 4; ++r) {
                float v = acc[m][n][r] + bv;
                if (RELU) v = fmaxf(v, 0.f);
                C[(rowb + r) * (size_t)ldc + col] = f2bf(v);
            }
        }
    }
}

// ---------------------------------------------------------------------------
// 128x128 MFMA GEMM (proven) for the small-N output head.
// ---------------------------------------------------------------------------
template<bool OBF16, bool RELU>
__global__ __launch_bounds__(256)
void gemm_mfma(const ushort_t* __restrict__ A, int lda,
               const ushort_t* __restrict__ A2, int lda2, int ksplit,
               const ushort_t* __restrict__ Bt,
               const float* __restrict__ bias,
               void* __restrict__ C, int ldc, int N, int K, int lgx)
{
    __shared__ ushort_t As[2][128 * 64];
    __shared__ ushort_t Bs[2][128 * 64];

    const int tid  = threadIdx.x;
    const int w    = tid >> 6;
    const int lane = tid & 63;
    const int wm   = w >> 1;
    const int wn   = w & 1;

    const int bid  = blockIdx.x;
    const int xcd  = bid & 7;
    const int slot = bid >> 3;
    const int x    = slot & ((1 << lgx) - 1);
    const int y    = xcd * 128 + (slot >> lgx);
    const size_t brow = (size_t)y * 128;
    const int    bcol = x * 128;

    const int fr   = lane & 15;
    const int fq   = lane >> 4;
    const int srow = lane >> 3;
    const int scol = (lane & 7) << 3;

    f32x4 acc[4][4];
#pragma unroll
    for (int i = 0; i < 4; ++i)
#pragma unroll
        for (int j = 0; j < 4; ++j) acc[i][j] = (f32x4){0.f, 0.f, 0.f, 0.f};

    const int NT = K >> 6;

    auto stage = [&](int buf, int k0) {
#pragma unroll
        for (int i = 0; i < 4; ++i) {
            const int c = (w << 2) + i;
            const int r = (c << 3) + srow;
            const ushort_t* asrc;
            if (k0 >= ksplit)
                asrc = A2 + (brow + r) * (size_t)lda2 + (k0 - ksplit) + scol;
            else
                asrc = A  + (brow + r) * (size_t)lda  + k0 + scol;
            gload_lds16(asrc, &As[buf][(c << 9) + lane * 8]);
            gload_lds16(Bt + (size_t)(bcol + r) * K + k0 + scol,
                        &Bs[buf][(c << 9) + lane * 8]);
        }
    };

    stage(0, 0);
    __syncthreads();

    for (int t = 0; t < NT; ++t) {
        const int cur = t & 1;
        if (t + 1 < NT) stage(cur ^ 1, (t + 1) << 6);
#pragma unroll
        for (int kk = 0; kk < 2; ++kk) {
            bf16x8 a[4], b[4];
#pragma unroll
            for (int f = 0; f < 4; ++f) {
                a[f] = *(const bf16x8*)&As[cur][(wm * 64 + f * 16 + fr) * 64 + kk * 32 + fq * 8];
                b[f] = *(const bf16x8*)&Bs[cur][(wn * 64 + f * 16 + fr) * 64 + kk * 32 + fq * 8];
            }
#pragma unroll
            for (int fm = 0; fm < 4; ++fm)
#pragma unroll
                for (int fn = 0; fn < 4; ++fn)
                    acc[fm][fn] = __builtin_amdgcn_mfma_f32_16x16x32_bf16(
                        a[fm], b[fn], acc[fm][fn], 0, 0, 0);
        }
        __syncthreads();
    }

#pragma unroll
    for (int fm = 0; fm < 4; ++fm) {
        const size_t rowb = brow + wm * 64 + fm * 16 + fq * 4;
#pragma unroll
        for (int fn = 0; fn < 4; ++fn) {
            const int col = bcol + wn * 64 + fn * 16 + fr;
            if (col < N) {
                const float bv = bias[col];
#pragma unroll
                for (int r = 0; r < 4; ++r) {
                    float v = acc[fm][fn][r] + bv;
                    if (RELU) v = fmaxf(v, 0.f);
                    const size_t idx = (rowb + r) * (size_t)ldc + col;
                    if (OBF16) ((ushort_t*)C)[idx] = f2bf(v);
                    else       ((float*)C)[idx]    = v;
                }
            }
        }
    }
}

// ---------------------------------------------------------------------------
// small prep kernels
// ---------------------------------------------------------------------------
__global__ __launch_bounds__(256)
void transpose_w(const float* __restrict__ W, ushort_t* __restrict__ Wt,
                 int K, int N, int Npad)
{
    int idx = blockIdx.x * 256 + threadIdx.x;
    if (idx >= Npad * K) return;
    int n = idx / K, k = idx - n * K;
    float v = (n < N) ? W[(size_t)k * N + n] : 0.f;
    Wt[idx] = f2bf(v);
}

__global__ __launch_bounds__(256)
void transpose_wk(const float* __restrict__ W, ushort_t* __restrict__ Wt,
                  int Ksrc, int N, int ldk, int kOff, float sign)
{
    int idx = blockIdx.x * 256 + threadIdx.x;
    if (idx >= N * Ksrc) return;
    int n = idx / Ksrc, k = idx - n * Ksrc;
    Wt[(size_t)n * ldk + kOff + k] = f2bf(sign * W[(size_t)k * N + n]);
}

__global__ __launch_bounds__(256)
void conv_f32_bf16(const float* __restrict__ src, ushort_t* __restrict__ dst)
{
    size_t q = (size_t)blockIdx.x * 256 + threadIdx.x;
    float4 v = ((const float4*)src)[q];
    ushort_t* d = dst + q * 4;
    d[0] = f2bf(v.x); d[1] = f2bf(v.y); d[2] = f2bf(v.z); d[3] = f2bf(v.w);
}

__global__ __launch_bounds__(256)
void fill_zero(ushort_t* __restrict__ p, int n)
{
    int i = blockIdx.x * 256 + threadIdx.x;
    if (i < n) p[i] = 0;
}

// g1bias = [bt1(512) | bp1(512)]
__global__ void pack_cat2(const float* __restrict__ a, const float* __restrict__ b,
                          float* __restrict__ o)
{
    int j = blockIdx.x * 256 + threadIdx.x;
    if (j < 512) o[j] = a[j];
    else if (j < 1024) o[j] = b[j - 512];
}

// pbias = [bk(32) | bq(32) | bv(128) | 0(64)]
__global__ void pack_bias(const float* __restrict__ bk, const float* __restrict__ bq,
                          const float* __restrict__ bv, float* __restrict__ pb)
{
    int j = threadIdx.x;
    float v = 0.f;
    if      (j < 32)  v = bk[j];
    else if (j < 64)  v = bq[j - 32];
    else if (j < 192) v = bv[j - 64];
    pb[j] = v;
}

// cbias[0:128] = bt2 - bp3; [128:256] = 0
__global__ void make_cbias(const float* __restrict__ bt2, const float* __restrict__ bp3,
                           float* __restrict__ cb)
{
    int j = threadIdx.x;
    cb[j] = (j < 128) ? (bt2[j] - bp3[j]) : 0.f;
}

// ---------------------------------------------------------------------------
// int_imp[b,a] = softmax_a( mean_c diff[b,a,c]^2 ), diff bf16 [BB,AA,256 stride]
// ---------------------------------------------------------------------------
__global__ __launch_bounds__(64)
void mse_softmax(const ushort_t* __restrict__ diff, float* __restrict__ int_imp)
{
    const int b = blockIdx.x, lane = threadIdx.x;
    __shared__ float m[AA];
    for (int a = 0; a < AA; ++a) {
        const uint32_t u = *(const uint32_t*)(diff + ((size_t)b * AA + a) * 256 + lane * 2);
        float d0 = bf2f((ushort_t)(u & 0xffff));
        float d1 = bf2f((ushort_t)(u >> 16));
        float s = d0 * d0 + d1 * d1;
#pragma unroll
        for (int off = 32; off > 0; off >>= 1) s += __shfl_down(s, off);
        if (lane == 0) m[a] = s * (1.f / 128.f);
    }
    __syncthreads();
    if (lane == 0) {
        float mx = -1e30f;
#pragma unroll
        for (int a = 0; a < AA; ++a) mx = fmaxf(mx, m[a]);
        float e[AA], den = 0.f;
#pragma unroll
        for (int a = 0; a < AA; ++a) { e[a] = __expf(m[a] - mx); den += e[a]; }
        float inv = 1.f / den;
#pragma unroll
        for (int a = 0; a < AA; ++a) int_imp[(size_t)b * AA + a] = e[a] * inv;
    }
}

// ---------------------------------------------------------------------------
// attention: kvq [BA][256] = [key(32)|qry(32)|val(128)|pad]; writes applied.
// ---------------------------------------------------------------------------
__global__ __launch_bounds__(256)
void attn_apply(const ushort_t* __restrict__ kvq, const float* __restrict__ Wa,
                const float* __restrict__ ba, const float* __restrict__ iimp,
                ushort_t* __restrict__ applied)
{
    const int b = blockIdx.x, t = threadIdx.x;
    __shared__ float klds[512], qlds[512];
    __shared__ ushort_t vlds[2048];
    __shared__ float part[16][17];
    __shared__ float kp[16];
    __shared__ float attn[16][17];

    for (int i = t; i < 512; i += 256) {
        int a = i >> 5, c = i & 31;
        const size_t base = ((size_t)b * AA + a) * 256;
        klds[i] = bf2f(kvq[base + c]);
        qlds[i] = bf2f(kvq[base + 32 + c]);
    }
    for (int i = t; i < 2048; i += 256) {
        int j = i >> 7, v = i & 127;
        vlds[i] = kvq[((size_t)b * AA + j) * 256 + 64 + v];
    }
    __syncthreads();

    {
        int j = t & 15, seg = t >> 4;
        float s = 0.f;
        for (int c = seg * 32; c < seg * 32 + 32; ++c)
            s += klds[c] * Wa[(32 + c) * 16 + j];
        part[j][seg] = s;
    }
    __syncthreads();
    if (t < 16) {
        float s = 0.f;
#pragma unroll
        for (int seg = 0; seg < 16; ++seg) s += part[t][seg];
        kp[t] = s;
    }
    __syncthreads();

    {
        int i = t >> 4, j = t & 15;
        float s = 0.f;
#pragma unroll
        for (int q = 0; q < 32; ++q) s += qlds[i * 32 + q] * Wa[q * 16 + j];
        attn[i][j] = s + kp[j] + ba[j];
    }
    __syncthreads();
    if (t < 16) {
        float mx = -1e30f;
#pragma unroll
        for (int j = 0; j < 16; ++j) mx = fmaxf(mx, attn[t][j]);
        float e[16], den = 0.f;
#pragma unroll
        for (int j = 0; j < 16; ++j) { e[j] = __expf(attn[t][j] - mx); den += e[j]; }
        float inv = 1.f / den;
#pragma unroll
        for (int j = 0; j < 16; ++j)
            attn[t][j] = e[j] * inv + 0.5f * iimp[b * 16 + j];
    }
    __syncthreads();

    for (int o = t; o < 2048; o += 256) {
        int i = o >> 7, v = o & 127;
        float s = 0.f;
#pragma unroll
        for (int j = 0; j < 16; ++j) s += attn[i][j] * bf2f(vlds[j * 128 + v]);
        applied[((size_t)b * AA + i) * 128 + v] = f2bf(s);
    }
}

// ---------------------------------------------------------------------------
// launch
// ---------------------------------------------------------------------------
extern "C" void kernel_launch(void* const* d_in, const int* in_sizes, int n_in,
                              void* d_out, int out_size, void* d_ws, size_t ws_size,
                              hipStream_t stream)
{
    const float* x      = (const float*)d_in[0];
    const float* hidden = (const float*)d_in[1];
    const float* Wk  = (const float*)d_in[2];
    const float* bk  = (const float*)d_in[3];
    const float* Wv  = (const float*)d_in[4];
    const float* bv  = (const float*)d_in[5];
    const float* Wq  = (const float*)d_in[6];
    const float* bq  = (const float*)d_in[7];
    const float* Wa  = (const float*)d_in[8];
    const float* ba  = (const float*)d_in[9];
    const float* Wt1 = (const float*)d_in[10];
    const float* bt1 = (const float*)d_in[11];
    const float* Wt2 = (const float*)d_in[12];
    const float* bt2 = (const float*)d_in[13];
    const float* Wp1 = (const float*)d_in[14];
    const float* bp1 = (const float*)d_in[15];
    const float* Wp2 = (const float*)d_in[16];
    const float* bp2 = (const float*)d_in[17];
    const float* Wp3 = (const float*)d_in[18];
    const float* bp3 = (const float*)d_in[19];
    const float* Wc  = (const float*)d_in[20];
    const float* bc  = (const float*)d_in[21];
    const float* W2  = (const float*)d_in[22];
    const float* b2  = (const float*)d_in[23];

    float*    out = (float*)d_out;
    ushort_t* ws  = (ushort_t*)d_ws;

    // ---- workspace (ushort elements) ------------------------------------
    ushort_t* xb  = ws;                        // [BA*512] x bf16
    ushort_t* ht2 = xb + (size_t)BA * 512;     // [BA*1024] [h_t | h_p1]
    ushort_t* hp2 = ht2 + (size_t)BA * 1024;   // [BA*512] h_p2
    ushort_t* WT  = hp2 + (size_t)BA * 512;
    // phase-2 aliases
    ushort_t* diff    = xb;                    // [BA*256] (x dead)
    ushort_t* kvq     = xb + (size_t)BA * 256; // [BA*256]
    ushort_t* hiddenb = hp2;                   // [BA*256] (h_p2 dead)
    ushort_t* applied = ht2;                   // [BA*128] (ht2 dead)
    ushort_t* comb    = ht2 + (size_t)BA * 128;// [BA*256]

    ushort_t* Bg1  = WT;                    // 1024*512  [Wt1^T ; Wp1^T]
    ushort_t* Wp2t = Bg1  + 1024 * 512;     // 512*512
    ushort_t* Dt   = Wp2t + 512 * 512;      // 256*1024  [Wt2^T | -Wp3^T ; 0]
    ushort_t* Wkvq = Dt   + 256 * 1024;     // 256*256   [Wk|Wq|Wv|0]^T
    ushort_t* Wct  = Wkvq + 256 * 256;      // 256*384
    ushort_t* W2t  = Wct  + 256 * 384;      // 128*256
    float* g1bias = (float*)(W2t + 128 * 256);
    float* pbias  = g1bias + 1024;
    float* cbias  = pbias + 256;
    float* iimp   = cbias + 256;            // BB*AA floats

    const dim3 blk(256);
    const int BIG = 1 << 30;

    // ---- weight prep -----------------------------------------------------
    transpose_w<<<1024, blk, 0, stream>>>(Wt1, Bg1,             512, 512, 512);
    transpose_w<<<1024, blk, 0, stream>>>(Wp1, Bg1 + 512 * 512, 512, 512, 512);
    transpose_w<<<1024, blk, 0, stream>>>(Wp2, Wp2t, 512, 512, 512);
    transpose_wk<<<256, blk, 0, stream>>>(Wt2, Dt, 512, 128, 1024, 0,    1.f);
    transpose_wk<<<256, blk, 0, stream>>>(Wp3, Dt, 512, 128, 1024, 512, -1.f);
    fill_zero<<<512, blk, 0, stream>>>(Dt + 128 * 1024, 128 * 1024);
    transpose_w<<<32,  blk, 0, stream>>>(Wk, Wkvq + 0 * 256,   256, 32, 32);
    transpose_w<<<32,  blk, 0, stream>>>(Wq, Wkvq + 32 * 256,  256, 32, 32);
    transpose_w<<<128, blk, 0, stream>>>(Wv, Wkvq + 64 * 256,  256, 128, 128);
    transpose_w<<<64,  blk, 0, stream>>>(Wk, Wkvq + 192 * 256, 256, 0, 64);   // zero pad
    transpose_w<<<384, blk, 0, stream>>>(Wc, Wct, 384, 256, 256);
    transpose_w<<<128, blk, 0, stream>>>(W2, W2t, 256, 64, 128);
    pack_cat2<<<4, 256, 0, stream>>>(bt1, bp1, g1bias);
    pack_bias<<<1, 256, 0, stream>>>(bk, bq, bv, pbias);
    make_cbias<<<1, 256, 0, stream>>>(bt2, bp3, cbias);

    // ---- phase 1: predictors ---------------------------------------------
    conv_f32_bf16<<<65536, blk, 0, stream>>>(x, xb);
    // [h_t | h_p1] = relu(x @ [Wt1|Wp1] + [bt1|bp1])
    gemm8p<true><<<2048, 512, 0, stream>>>(
        xb, 512, xb, 512, BIG, Bg1, g1bias, ht2, 1024, 512, 2, 64);
    // h_p2 = relu(h_p1 @ Wp2 + bp2)
    gemm8p<true><<<1024, 512, 0, stream>>>(
        ht2 + 512, 1024, ht2 + 512, 1024, BIG, Wp2t, bp2, hp2, 512, 512, 1, 64);
    // diff = [h_t | h_p2] @ [Wt2;-Wp3] + (bt2-bp3)  (N padded to 256)
    gemm8p<false><<<512, 512, 0, stream>>>(
        ht2, 1024, hp2, 512, 512, Dt, cbias, diff, 256, 1024, 0, 64);
    mse_softmax<<<BB, 64, 0, stream>>>(diff, iimp);

    // ---- phase 2: communicate --------------------------------------------
    conv_f32_bf16<<<32768, blk, 0, stream>>>(hidden, hiddenb);
    // kvq = hidden @ [Wk|Wq|Wv|0] + pbias  (N padded to 256)
    gemm8p<false><<<512, 512, 0, stream>>>(
        hiddenb, 256, hiddenb, 256, BIG, Wkvq, pbias, kvq, 256, 256, 0, 64);
    attn_apply<<<BB, blk, 0, stream>>>(kvq, Wa, ba, iimp, applied);

    // ---- phase 3: combine + head -----------------------------------------
    // comb = relu([applied|hidden] @ Wc + bc)
    gemm8p<true><<<512, 512, 0, stream>>>(
        applied, 128, hiddenb, 256, 128, Wct, bc, comb, 256, 384, 0, 64);
    // out = comb @ W2 + b2 (f32)
    gemm_mfma<false, false><<<1024, blk, 0, stream>>>(
        comb, 256, comb, 256, BIG, W2t, b2, out, 64, 64, 256, 0);
}